// Round 1
// baseline (370.267 us; speedup 1.0000x reference)
//
#include <hip/hip_runtime.h>
#include <hip/hip_bf16.h>
#include <math.h>

#define DIM 192
#define NB  16
#define NH  64
#define NW  64
#define NT  4096   // NH*NW

// ---------------------------------------------------------------------------
// Kernel 1: fold alpha0*I + alpha1*w1(1x1) + alpha2*w3(3x3) + alpha3*w5(5x5)
// into one 5x5 depthwise kernel per channel.
__global__ void k_combine_w(const float* __restrict__ w1,
                            const float* __restrict__ w3,
                            const float* __restrict__ w5,
                            const float* __restrict__ alpha,
                            float* __restrict__ wc) {
    int c = threadIdx.x;
    if (c >= DIM) return;
    float a0 = alpha[0], a1 = alpha[1], a2 = alpha[2], a3 = alpha[3];
    #pragma unroll
    for (int kh = 0; kh < 5; ++kh) {
        #pragma unroll
        for (int kw = 0; kw < 5; ++kw) {
            float v = a3 * w5[c * 25 + kh * 5 + kw];
            if (kh >= 1 && kh <= 3 && kw >= 1 && kw <= 3)
                v += a2 * w3[c * 9 + (kh - 1) * 3 + (kw - 1)];
            if (kh == 2 && kw == 2)
                v += a0 + a1 * w1[c];
            wc[c * 25 + kh * 5 + kw] = v;
        }
    }
}

// ---------------------------------------------------------------------------
// Kernel 2: depthwise 5x5 conv, sliding-column register window.
// block = 192 threads (one per channel), grid = B*H. Each thread walks w=0..63.
__global__ __launch_bounds__(192) void k_conv(const float* __restrict__ x,
                                              const float* __restrict__ wc,
                                              float* __restrict__ xs) {
    int c  = threadIdx.x;
    int bh = blockIdx.x;
    int b = bh >> 6, h = bh & 63;
    const float* xb = x + (size_t)b * NT * DIM + c;
    float* xsrow = xs + ((size_t)b * NT + (size_t)h * NW) * DIM + c;

    float wgt[25];
    #pragma unroll
    for (int j = 0; j < 25; ++j) wgt[j] = wc[c * 25 + j];

    const float* rowp[5];
    bool rok[5];
    #pragma unroll
    for (int dh = 0; dh < 5; ++dh) {
        int hh = h + dh - 2;
        rok[dh] = (hh >= 0 && hh < NH);
        rowp[dh] = xb + (size_t)(rok[dh] ? hh : 0) * NW * DIM;
    }

    // window win[dh][j]: column (w-2+j) for the current output w
    float win[5][5];
    #pragma unroll
    for (int dh = 0; dh < 5; ++dh) {
        win[dh][0] = 0.f; win[dh][1] = 0.f; win[dh][2] = 0.f;
        win[dh][3] = rok[dh] ? rowp[dh][(size_t)0 * DIM] : 0.f;  // col 0
        win[dh][4] = rok[dh] ? rowp[dh][(size_t)1 * DIM] : 0.f;  // col 1
    }

    for (int w = 0; w < NW; ++w) {
        int wcol = w + 2;
        bool cok = (wcol < NW);
        #pragma unroll
        for (int dh = 0; dh < 5; ++dh) {
            win[dh][0] = win[dh][1];
            win[dh][1] = win[dh][2];
            win[dh][2] = win[dh][3];
            win[dh][3] = win[dh][4];
            win[dh][4] = (rok[dh] && cok) ? rowp[dh][(size_t)wcol * DIM] : 0.f;
        }
        float acc = 0.f;
        #pragma unroll
        for (int dh = 0; dh < 5; ++dh)
            #pragma unroll
            for (int dw = 0; dw < 5; ++dw)
                acc = fmaf(win[dh][dw], wgt[dh * 5 + dw], acc);
        xsrow[(size_t)w * DIM] = acc;
    }
}

// ---------------------------------------------------------------------------
// Shared GEMM config: M-tile 128, N-tile 64, K-tile 32, 256 threads, 8x4/thread.
#define MT 128
#define NT_ 64
#define KT 32
#define LDA 132   // 132*4 = 528 B, multiple of 16 -> aligned float4 rows
#define LDB 68    // 272 B, multiple of 16

// Kernel 3: k/v/r projections. A = xs (M x K row-major), B = W (N x K row-major,
// torch Linear). Writes output TRANSPOSED: Out[(b*DIM + n)*NT + t], m = b*NT+t.
// mat 2 (r) gets sigmoid in the epilogue.
__global__ __launch_bounds__(256) void k_gemm_qkv(
        const float* __restrict__ xs,
        const float* __restrict__ Wk, const float* __restrict__ Wv,
        const float* __restrict__ Wr,
        float* __restrict__ kT, float* __restrict__ vT, float* __restrict__ srT) {
    __shared__ float As[KT][LDA];
    __shared__ float Bs[KT][LDB];
    int tid = threadIdx.x;
    int m0 = blockIdx.x * MT;
    int n0 = blockIdx.y * NT_;
    int mat = blockIdx.z;
    const float* W = (mat == 0) ? Wk : (mat == 1 ? Wv : Wr);
    float* Out = (mat == 0) ? kT : (mat == 1 ? vT : srT);

    float acc[8][4];
    #pragma unroll
    for (int i = 0; i < 8; ++i)
        #pragma unroll
        for (int j = 0; j < 4; ++j) acc[i][j] = 0.f;

    int a_m  = tid >> 3;         // 0..31
    int a_k4 = (tid & 7) * 4;    // 0..28
    int tmy = (tid >> 4) * 8;    // m offset within tile
    int tnx = (tid & 15) * 4;    // n offset within tile

    for (int k0 = 0; k0 < DIM; k0 += KT) {
        #pragma unroll
        for (int r = 0; r < 4; ++r) {          // stage A with transpose
            int mm = a_m + r * 32;
            float4 v = *(const float4*)&xs[(size_t)(m0 + mm) * DIM + k0 + a_k4];
            As[a_k4 + 0][mm] = v.x; As[a_k4 + 1][mm] = v.y;
            As[a_k4 + 2][mm] = v.z; As[a_k4 + 3][mm] = v.w;
        }
        #pragma unroll
        for (int r = 0; r < 2; ++r) {          // stage B with transpose
            int nn = a_m + r * 32;
            float4 v = *(const float4*)&W[(size_t)(n0 + nn) * DIM + k0 + a_k4];
            Bs[a_k4 + 0][nn] = v.x; Bs[a_k4 + 1][nn] = v.y;
            Bs[a_k4 + 2][nn] = v.z; Bs[a_k4 + 3][nn] = v.w;
        }
        __syncthreads();
        #pragma unroll
        for (int kk = 0; kk < KT; ++kk) {
            float4 a0 = *(const float4*)&As[kk][tmy];
            float4 a1 = *(const float4*)&As[kk][tmy + 4];
            float4 b0 = *(const float4*)&Bs[kk][tnx];
            float av[8] = {a0.x, a0.y, a0.z, a0.w, a1.x, a1.y, a1.z, a1.w};
            float bv[4] = {b0.x, b0.y, b0.z, b0.w};
            #pragma unroll
            for (int i = 0; i < 8; ++i)
                #pragma unroll
                for (int j = 0; j < 4; ++j)
                    acc[i][j] = fmaf(av[i], bv[j], acc[i][j]);
        }
        __syncthreads();
    }

    if (mat == 2) {
        #pragma unroll
        for (int i = 0; i < 8; ++i)
            #pragma unroll
            for (int j = 0; j < 4; ++j)
                acc[i][j] = 1.0f / (1.0f + expf(-acc[i][j]));
    }

    int b  = m0 >> 12;                 // m0 / 4096
    int t0 = (m0 & 4095) + tmy;
    #pragma unroll
    for (int j = 0; j < 4; ++j) {
        size_t rowbase = ((size_t)(b * DIM + n0 + tnx + j)) * NT + t0;
        *(float4*)&Out[rowbase]     = make_float4(acc[0][j], acc[1][j], acc[2][j], acc[3][j]);
        *(float4*)&Out[rowbase + 4] = make_float4(acc[4][j], acc[5][j], acc[6][j], acc[7][j]);
    }
}

// ---------------------------------------------------------------------------
// Kernel 4: bidirectional WKV4. One block per (b,c); 256 threads x 16 t each.
// Blocked linear-recurrence scan: local Horner + 256-wide Hillis-Steele with
// ratio ew^16 in LDS (forward and backward). Fuses z = sigmoid(r) * y.
__global__ __launch_bounds__(256) void k_wkv(
        const float* __restrict__ kT, const float* __restrict__ vT,
        const float* __restrict__ srT, const float* __restrict__ decay,
        const float* __restrict__ boost, float* __restrict__ zT) {
    __shared__ float sa[256], sb[256];
    int bc = blockIdx.x;               // b*DIM + c
    int c = bc % DIM;
    size_t base = (size_t)bc * NT;
    int tid = threadIdx.x;
    int t0 = tid * 16;

    float w  = decay[c] * (1.0f / 4096.0f);
    float u  = boost[c] * (1.0f / 4096.0f);
    float ew = expf(-w);
    float eu = expf(u);

    float ek[16], ekv[16], vv[16];
    #pragma unroll
    for (int j = 0; j < 16; j += 4) {
        float4 k4 = *(const float4*)&kT[base + t0 + j];
        float4 v4 = *(const float4*)&vT[base + t0 + j];
        ek[j + 0] = expf(k4.x); ek[j + 1] = expf(k4.y);
        ek[j + 2] = expf(k4.z); ek[j + 3] = expf(k4.w);
        vv[j + 0] = v4.x; vv[j + 1] = v4.y; vv[j + 2] = v4.z; vv[j + 3] = v4.w;
        ekv[j + 0] = ek[j + 0] * v4.x; ekv[j + 1] = ek[j + 1] * v4.y;
        ekv[j + 2] = ek[j + 2] * v4.z; ekv[j + 3] = ek[j + 3] * v4.w;
    }

    // ew^16 via 4 squarings
    float r = ew * ew; r = r * r; r = r * r; r = r * r;

    // ---- forward: local totals, block scan, per-thread carry ----
    float La = 0.f, Lb = 0.f;
    #pragma unroll
    for (int j = 0; j < 16; ++j) { La = fmaf(ew, La, ekv[j]); Lb = fmaf(ew, Lb, ek[j]); }
    sa[tid] = La; sb[tid] = Lb;
    __syncthreads();
    float f = r;
    for (int d = 1; d < 256; d <<= 1) {
        float ta = (tid >= d) ? sa[tid - d] : 0.f;
        float tb = (tid >= d) ? sb[tid - d] : 0.f;
        __syncthreads();
        sa[tid] = fmaf(f, ta, sa[tid]);
        sb[tid] = fmaf(f, tb, sb[tid]);
        __syncthreads();
        f = f * f;
    }
    float Ca = (tid > 0) ? sa[tid - 1] : 0.f;
    float Cb = (tid > 0) ? sb[tid - 1] : 0.f;
    __syncthreads();

    // ---- backward: local totals (ascending powers), reversed block scan ----
    float Ra = 0.f, Rb = 0.f;
    #pragma unroll
    for (int j = 15; j >= 0; --j) { Ra = fmaf(ew, Ra, ekv[j]); Rb = fmaf(ew, Rb, ek[j]); }
    sa[255 - tid] = Ra; sb[255 - tid] = Rb;
    __syncthreads();
    f = r;
    for (int d = 1; d < 256; d <<= 1) {
        float ta = (tid >= d) ? sa[tid - d] : 0.f;
        float tb = (tid >= d) ? sb[tid - d] : 0.f;
        __syncthreads();
        sa[tid] = fmaf(f, ta, sa[tid]);
        sb[tid] = fmaf(f, tb, sb[tid]);
        __syncthreads();
        f = f * f;
    }
    float Da = (tid < 255) ? sa[254 - tid] : 0.f;
    float Db = (tid < 255) ? sb[254 - tid] : 0.f;

    // ---- backward local pass (store exclusive suffix states) ----
    float ab[16], bb[16];
    {
        float a = Da, bv = Db;
        #pragma unroll
        for (int j = 15; j >= 0; --j) {
            ab[j] = a; bb[j] = bv;
            a  = fmaf(ew, a, ekv[j]);
            bv = fmaf(ew, bv, ek[j]);
        }
    }
    // ---- forward local pass + combine ----
    float outv[16];
    {
        float a = Ca, bv = Cb;
        #pragma unroll
        for (int j = 0; j < 16; ++j) {
            float af = a, bf = bv;
            a  = fmaf(ew, a, ekv[j]);
            bv = fmaf(ew, bv, ek[j]);
            float euk = eu * ek[j];
            float num = af + ab[j] + euk * vv[j];
            float den = bf + bb[j] + euk;
            outv[j] = num / den;
        }
    }
    #pragma unroll
    for (int j = 0; j < 16; j += 4) {
        float4 s4 = *(const float4*)&srT[base + t0 + j];
        float4 o;
        o.x = s4.x * outv[j + 0];
        o.y = s4.y * outv[j + 1];
        o.z = s4.z * outv[j + 2];
        o.w = s4.w * outv[j + 3];
        *(float4*)&zT[base + t0 + j] = o;
    }
}

// ---------------------------------------------------------------------------
// Kernel 5: output projection. A = zT in (B,C,T) layout, i.e. already k-major
// along m (no transpose needed when staging). B = Wo (N x K row-major).
// out[(b*NT + t)*DIM + n].
__global__ __launch_bounds__(256) void k_gemm_out(
        const float* __restrict__ zT, const float* __restrict__ Wo,
        float* __restrict__ out) {
    __shared__ float As[KT][LDA];
    __shared__ float Bs[KT][LDB];
    int tid = threadIdx.x;
    int m0 = blockIdx.x * MT;
    int n0 = blockIdx.y * NT_;
    int b  = m0 >> 12;
    int t0 = m0 & 4095;

    float acc[8][4];
    #pragma unroll
    for (int i = 0; i < 8; ++i)
        #pragma unroll
        for (int j = 0; j < 4; ++j) acc[i][j] = 0.f;

    int a_kk = tid >> 5;          // 0..7
    int a_c4 = (tid & 31) * 4;    // 0..124
    int b_n  = tid >> 3;          // 0..31
    int b_k4 = (tid & 7) * 4;
    int tmy = (tid >> 4) * 8;
    int tnx = (tid & 15) * 4;

    for (int k0 = 0; k0 < DIM; k0 += KT) {
        #pragma unroll
        for (int r = 0; r < 4; ++r) {          // stage A directly (k-major rows)
            int kk = a_kk + r * 8;
            float4 v = *(const float4*)&zT[((size_t)(b * DIM + k0 + kk)) * NT + t0 + a_c4];
            *(float4*)&As[kk][a_c4] = v;
        }
        #pragma unroll
        for (int r = 0; r < 2; ++r) {          // stage B with transpose
            int nn = b_n + r * 32;
            float4 v = *(const float4*)&Wo[(size_t)(n0 + nn) * DIM + k0 + b_k4];
            Bs[b_k4 + 0][nn] = v.x; Bs[b_k4 + 1][nn] = v.y;
            Bs[b_k4 + 2][nn] = v.z; Bs[b_k4 + 3][nn] = v.w;
        }
        __syncthreads();
        #pragma unroll
        for (int kk = 0; kk < KT; ++kk) {
            float4 a0 = *(const float4*)&As[kk][tmy];
            float4 a1 = *(const float4*)&As[kk][tmy + 4];
            float4 b0 = *(const float4*)&Bs[kk][tnx];
            float av[8] = {a0.x, a0.y, a0.z, a0.w, a1.x, a1.y, a1.z, a1.w};
            float bv[4] = {b0.x, b0.y, b0.z, b0.w};
            #pragma unroll
            for (int i = 0; i < 8; ++i)
                #pragma unroll
                for (int j = 0; j < 4; ++j)
                    acc[i][j] = fmaf(av[i], bv[j], acc[i][j]);
        }
        __syncthreads();
    }

    #pragma unroll
    for (int i = 0; i < 8; ++i) {
        size_t rowbase = (size_t)(m0 + tmy + i) * DIM + n0 + tnx;
        *(float4*)&out[rowbase] = make_float4(acc[i][0], acc[i][1], acc[i][2], acc[i][3]);
    }
}

// ---------------------------------------------------------------------------
extern "C" void kernel_launch(void* const* d_in, const int* in_sizes, int n_in,
                              void* d_out, int out_size, void* d_ws, size_t ws_size,
                              hipStream_t stream) {
    const float* x     = (const float*)d_in[0];
    const float* w1    = (const float*)d_in[1];
    const float* w3    = (const float*)d_in[2];
    const float* w5    = (const float*)d_in[3];
    const float* alpha = (const float*)d_in[4];
    const float* Wk    = (const float*)d_in[5];
    const float* Wv    = (const float*)d_in[6];
    const float* Wr    = (const float*)d_in[7];
    const float* Wo    = (const float*)d_in[8];
    const float* decay = (const float*)d_in[9];
    const float* boost = (const float*)d_in[10];
    float* out = (float*)d_out;
    float* ws  = (float*)d_ws;

    const size_t BIG = (size_t)NB * NT * DIM;   // 12,582,912 floats
    float* wc  = ws;                 // 4800 floats
    float* xs  = ws + 8192;          // also reused as zT after gemm_qkv
    float* kT  = xs + BIG;
    float* vT  = kT + BIG;
    float* srT = vT + BIG;

    hipLaunchKernelGGL(k_combine_w, dim3(1), dim3(192), 0, stream, w1, w3, w5, alpha, wc);
    hipLaunchKernelGGL(k_conv, dim3(NB * NH), dim3(DIM), 0, stream, x, wc, xs);
    hipLaunchKernelGGL(k_gemm_qkv, dim3(65536 / MT, DIM / NT_, 3), dim3(256), 0, stream,
                       xs, Wk, Wv, Wr, kT, vT, srT);
    hipLaunchKernelGGL(k_wkv, dim3(NB * DIM), dim3(256), 0, stream,
                       kT, vT, srT, decay, boost, xs /* zT reuses xs */);
    hipLaunchKernelGGL(k_gemm_out, dim3(65536 / MT, DIM / NT_), dim3(256), 0, stream,
                       xs /* zT */, Wo, out);
}